// Round 2
// baseline (3180.398 us; speedup 1.0000x reference)
//
#include <hip/hip_runtime.h>
#include <math.h>

#define NCH     129
#define NT      250
#define DMODEL  128
#define DINNER  256
#define DSTATE  16
#define NHEADS  4
#define DPROJ   548   // z(256) + xBC(288) + dt(4)
#define XBC0    256   // zx col offset of conv channels (xh at 256.., B/C at 512..)
#define DT0     544   // zx col offset of dt heads

__device__ __forceinline__ float silu_f(float x) { return x / (1.f + expf(-x)); }

// ---------- v[i] = sum_d head_w[0,d]*out_proj_w[d,i]  (exact linear fusion) ----------
__global__ __launch_bounds__(256) void k_prep_v(const float* __restrict__ head_w,
                                                const float* __restrict__ out_proj_w,
                                                float* __restrict__ v) {
    int i = threadIdx.x;
    float acc = 0.f;
    for (int d = 0; d < DMODEL; ++d)
        acc += head_w[d] * out_proj_w[(size_t)d * DINNER + i];
    v[i] = acc;
}

__global__ void k_init_out(float* __restrict__ out, const float* __restrict__ head_b, int n) {
    int i = blockIdx.x * blockDim.x + threadIdx.x;
    if (i < n) out[i] = head_b[0];
}

// ---------- K1: u[b,t,d] = sum_c x[b,c,t]*mixer_w[d,c] + mixer_b[d] ----------
__global__ __launch_bounds__(256) void k_u(const float* __restrict__ x,       // [Bc,129,250] (offset)
                                           const float* __restrict__ mixer_w, // [128,129]
                                           const float* __restrict__ mixer_b, // [128]
                                           float* __restrict__ u_s) {         // [Bc,250,128]
    __shared__ float xs[NCH][64];          // [c][t_local]
    __shared__ float ut[64][DMODEL + 1];   // transpose buffer, padded
    int b  = blockIdx.y;
    int t0 = blockIdx.x * 64;
    const float* xb = x + (size_t)b * NCH * NT;

    for (int idx = threadIdx.x; idx < NCH * 64; idx += 256) {
        int c = idx >> 6, tl = idx & 63;
        int t = t0 + tl;
        xs[c][tl] = (t < NT) ? xb[(size_t)c * NT + t] : 0.f;   // coalesced along t
    }
    __syncthreads();

    int tl = threadIdx.x & 63, dg = threadIdx.x >> 6;
    for (int d = dg; d < DMODEL; d += 4) {                     // d wave-uniform -> scalar loads
        float acc = mixer_b[d];
        for (int c = 0; c < NCH; ++c)
            acc = fmaf(xs[c][tl], mixer_w[d * NCH + c], acc);
        ut[tl][d] = acc;
    }
    __syncthreads();

    for (int idx = threadIdx.x; idx < 64 * DMODEL; idx += 256) {
        int r = idx >> 7, d = idx & 127;
        int t = t0 + r;
        if (t < NT) u_s[((size_t)b * NT + t) * DMODEL + d] = ut[r][d];  // coalesced along d
    }
}

// ---------- K2: zx[b,t,j] = sum_d u[b,t,d]*in_proj_w[j,d] ----------
__global__ __launch_bounds__(256) void k_proj(const float* __restrict__ u_s,       // [Bc,250,128]
                                              const float* __restrict__ in_proj_w, // [548,128]
                                              float* __restrict__ zx_s) {          // [Bc,250,548]
    __shared__ float us[64][DMODEL + 1];
    __shared__ float ip[64][DMODEL + 1];
    int b  = blockIdx.z;
    int t0 = blockIdx.y * 64;
    int j0 = blockIdx.x * 64;

    for (int idx = threadIdx.x; idx < 64 * DMODEL; idx += 256) {
        int r = idx >> 7, d = idx & 127;
        int t = t0 + r;
        us[r][d] = (t < NT) ? u_s[((size_t)b * NT + t) * DMODEL + d] : 0.f;
        int j = j0 + r;
        ip[r][d] = (j < DPROJ) ? in_proj_w[(size_t)j * DMODEL + d] : 0.f;
    }
    __syncthreads();

    int jl = threadIdx.x & 63, tg = threadIdx.x >> 6;
    int j = j0 + jl;
    for (int tt = tg; tt < 64; tt += 4) {
        int t = t0 + tt;
        if (t >= NT) break;
        float acc = 0.f;
        for (int d = 0; d < DMODEL; ++d)
            acc = fmaf(us[tt][d], ip[jl][d], acc);   // us: broadcast; ip: conflict-free (pad 129)
        if (j < DPROJ) zx_s[((size_t)b * NT + t) * DPROJ + j] = acc;  // coalesced along j
    }
}

// ---------- K3: fused causal conv + silu + dt/dA + SSM scan ----------
// Block = 320 threads (5 waves), one block per batch element.
//   tid 0..255  : xh channel ch=tid (zx col 256+tid), conv -> silu -> scan lane
//   tid 256..287: B/C channel (zx col 256+tid = 512+cc), conv -> silu -> LDS
//   tid 288..291: head h=tid-288, dt=softplus(zx[544+h]+bias), dA=exp(dt*A) -> LDS
__global__ __launch_bounds__(320) void k_scan(const float* __restrict__ zx_s,
                                              const float* __restrict__ conv_w,  // [288,4]
                                              const float* __restrict__ conv_b,  // [288]
                                              const float* __restrict__ dt_bias, // [4]
                                              const float* __restrict__ A_log,   // [4]
                                              const float* __restrict__ Dv,      // [4]
                                              float* __restrict__ y_s) {         // [Bc,250,256]
    __shared__ float sm_bc[2 * DSTATE];
    __shared__ float sm_dt[NHEADS];
    __shared__ float sm_dA[NHEADS];

    int b   = blockIdx.x;
    int tid = threadIdx.x;

    float w0 = 0.f, w1 = 0.f, w2 = 0.f, w3 = 0.f, cb = 0.f;
    float Dh = 0.f, Ah = 0.f, dtb = 0.f;
    int h = 0;
    if (tid < 288) {                     // conv role (xh or B/C)
        int ch = tid;                    // conv channel index 0..287
        w0 = conv_w[ch * 4 + 0]; w1 = conv_w[ch * 4 + 1];
        w2 = conv_w[ch * 4 + 2]; w3 = conv_w[ch * 4 + 3];
        cb = conv_b[ch];
        if (tid < 256) { h = tid >> 6; Dh = Dv[h]; }
    } else if (tid < 292) {              // dt role
        h   = tid - 288;
        dtb = dt_bias[h];
        Ah  = -expf(A_log[h]);
    }

    float r1 = 0.f, r2 = 0.f, r3 = 0.f;  // raw[t-1], raw[t-2], raw[t-3]
    float hs[DSTATE];
#pragma unroll
    for (int n = 0; n < DSTATE; ++n) hs[n] = 0.f;

    const float* zb = zx_s + (size_t)b * NT * DPROJ;

    for (int t = 0; t < NT; ++t) {
        const float* zrow = zb + (size_t)t * DPROJ;
        float xv = 0.f;
        if (tid < 288) {
            float raw = zrow[XBC0 + tid];
            float cv = fmaf(w3, raw, fmaf(w2, r1, fmaf(w1, r2, fmaf(w0, r3, cb))));
            r3 = r2; r2 = r1; r1 = raw;
            cv = silu_f(cv);
            if (tid < 256) xv = cv;
            else           sm_bc[tid - 256] = cv;
        } else if (tid < 292) {
            float val = zrow[DT0 + h] + dtb;
            float dt = (val > 20.f) ? val : log1pf(expf(val));
            sm_dt[h] = dt;
            sm_dA[h] = expf(dt * Ah);
        }
        __syncthreads();
        if (tid < 256) {
            float dtv = sm_dt[h], dAv = sm_dA[h];
            float dx = dtv * xv;
            float y = 0.f;
#pragma unroll
            for (int n = 0; n < DSTATE; ++n) {
                hs[n] = fmaf(hs[n], dAv, dx * sm_bc[n]);        // B
                y = fmaf(hs[n], sm_bc[DSTATE + n], y);          // C
            }
            y_s[((size_t)b * NT + t) * DINNER + tid] = fmaf(Dh, xv, y);
        }
        __syncthreads();   // protect sm_bc/sm_dt before next t overwrites
    }
}

// ---------- K4: gate*silu(z), RMSNorm, dot v, atomic mean ----------
__global__ __launch_bounds__(256) void k_final(const float* __restrict__ y_s,
                                               const float* __restrict__ zx_s,
                                               const float* __restrict__ norm_w,
                                               const float* __restrict__ v,
                                               float* __restrict__ out, int boff) {
    int t = blockIdx.x;
    int b = blockIdx.y;
    int i = threadIdx.x;
    size_t row = (size_t)b * NT + t;
    float y = y_s[row * DINNER + i];
    float z = zx_s[row * DPROJ + i];       // z slice = zx cols [0,256)
    float val = y * silu_f(z);

    __shared__ float red[4];
    __shared__ float red2[4];
    float ss = val * val;
#pragma unroll
    for (int o = 32; o > 0; o >>= 1) ss += __shfl_down(ss, o);
    int wid = i >> 6;
    if ((i & 63) == 0) red[wid] = ss;
    __syncthreads();
    float tot = red[0] + red[1] + red[2] + red[3];
    float rinv = rsqrtf(tot * (1.f / DINNER) + 1e-5f);
    float contrib = val * rinv * norm_w[i] * v[i];
#pragma unroll
    for (int o = 32; o > 0; o >>= 1) contrib += __shfl_down(contrib, o);
    if ((i & 63) == 0) red2[wid] = contrib;
    __syncthreads();
    if (i == 0)
        atomicAdd(out + (boff + b), (red2[0] + red2[1] + red2[2] + red2[3]) * (1.f / NT));
}

extern "C" void kernel_launch(void* const* d_in, const int* in_sizes, int n_in,
                              void* d_out, int out_size, void* d_ws, size_t ws_size,
                              hipStream_t stream) {
    const float* x         = (const float*)d_in[0];
    const float* mixer_w   = (const float*)d_in[1];
    const float* mixer_b   = (const float*)d_in[2];
    const float* in_proj_w = (const float*)d_in[3];
    const float* conv_w    = (const float*)d_in[4];
    const float* conv_b    = (const float*)d_in[5];
    const float* dt_bias   = (const float*)d_in[6];
    const float* A_log     = (const float*)d_in[7];
    const float* Dp        = (const float*)d_in[8];
    const float* norm_w    = (const float*)d_in[9];
    const float* out_proj_w= (const float*)d_in[10];
    const float* head_w    = (const float*)d_in[11];
    const float* head_b    = (const float*)d_in[12];
    float* out = (float*)d_out;

    int B = in_sizes[0] / (NCH * NT);   // 512

    // ws floats: vv(256) + per-batch [u 250*128 | zx 250*548 | y 250*256]
    const size_t perB   = (size_t)NT * (DMODEL + DPROJ + DINNER);  // 233000
    const size_t fixedF = DINNER;
    int Bc = B;
    while (Bc > 1 && (fixedF + (size_t)Bc * perB) * 4 > ws_size) Bc >>= 1;

    float* ws   = (float*)d_ws;
    float* vv   = ws;
    float* u_s  = vv + DINNER;
    float* zx_s = u_s + (size_t)Bc * NT * DMODEL;
    float* y_s  = zx_s + (size_t)Bc * NT * DPROJ;

    k_prep_v<<<1, 256, 0, stream>>>(head_w, out_proj_w, vv);
    k_init_out<<<(out_size + 255) / 256, 256, 0, stream>>>(out, head_b, out_size);

    for (int boff = 0; boff < B; boff += Bc) {
        int bc = (boff + Bc <= B) ? Bc : (B - boff);
        k_u   <<<dim3(4, bc),    256, 0, stream>>>(x + (size_t)boff * NCH * NT, mixer_w, mixer_b, u_s);
        k_proj<<<dim3(9, 4, bc), 256, 0, stream>>>(u_s, in_proj_w, zx_s);
        k_scan<<<bc,             320, 0, stream>>>(zx_s, conv_w, conv_b, dt_bias, A_log, Dp, y_s);
        k_final<<<dim3(NT, bc),  256, 0, stream>>>(y_s, zx_s, norm_w, vv, out, boff);
    }
}

// Round 3
// 1753.436 us; speedup vs baseline: 1.8138x; 1.8138x over previous
//
#include <hip/hip_runtime.h>
#include <math.h>

#define NCH     129
#define NT      250
#define DMODEL  128
#define DINNER  256
#define DSTATE  16
#define NHEADS  4
#define DPROJ   548   // z(256) + xh(256) + B(16) + C(16) + dt(4)
#define TC      32    // timestep chunk (250 = 7*32 + 26)

template<int N> struct IC { static constexpr int value = N; };

__device__ __forceinline__ float silu_f(float x) { return x / (1.f + expf(-x)); }

// DPP butterfly: after 6 steps lane 63 holds the 64-lane sum (VALU pipe, no DS).
template<int CTRL>
__device__ __forceinline__ float dstep(float v) {
    int t = __builtin_amdgcn_update_dpp(0, __float_as_int(v), CTRL, 0xF, 0xF, true);
    return v + __int_as_float(t);
}
__device__ __forceinline__ float wave_sum63(float v) {
    v = dstep<0xB1>(v);   // quad_perm xor1
    v = dstep<0x4E>(v);   // quad_perm xor2
    v = dstep<0x141>(v);  // row_half_mirror
    v = dstep<0x140>(v);  // row_mirror -> every lane has its 16-row sum
    v = dstep<0x142>(v);  // row_bcast15
    v = dstep<0x143>(v);  // row_bcast31 -> lane63 = total
    return v;
}
__device__ __forceinline__ float rdlane(float v, int l) {
    return __uint_as_float(__builtin_amdgcn_readlane(__float_as_uint(v), l));
}

// ---------- prep: W2t[c][j] = sum_d in_proj_w[j,d]*mixer_w[d,c]; bias2[j] = in_proj_w[j,:]@mixer_b ----------
__global__ __launch_bounds__(256) void k_prep_w2(const float* __restrict__ in_proj_w,
                                                 const float* __restrict__ mixer_w,
                                                 const float* __restrict__ mixer_b,
                                                 float* __restrict__ w2t,
                                                 float* __restrict__ bias2) {
    int j = blockIdx.x;          // 0..547
    int c = threadIdx.x;
    if (c < NCH) {
        float acc = 0.f;
        for (int d = 0; d < DMODEL; ++d)
            acc += in_proj_w[j * DMODEL + d] * mixer_w[d * NCH + c];
        w2t[(size_t)c * DPROJ + j] = acc;
    } else if (c == NCH) {
        float acc = 0.f;
        for (int d = 0; d < DMODEL; ++d)
            acc += in_proj_w[j * DMODEL + d] * mixer_b[d];
        bias2[j] = acc;
    }
}

// ---------- prep: v[i] = sum_d head_w[0,d]*out_proj_w[d,i] (exact linear fusion) ----------
__global__ __launch_bounds__(256) void k_prep_v(const float* __restrict__ head_w,
                                                const float* __restrict__ out_proj_w,
                                                float* __restrict__ v) {
    int i = threadIdx.x;
    float acc = 0.f;
    for (int d = 0; d < DMODEL; ++d)
        acc += head_w[d] * out_proj_w[(size_t)d * DINNER + i];
    v[i] = acc;
}

// ---------- fully fused: GEMM (registers) + conv + dt + scan + gate + RMSNorm + dot v + mean ----------
// One block per batch element. 320 threads = 5 waves.
//   tid 0..255 (waves 0-3): lane owns zx cols {p, 256+p}: z-gate + conv/xh channel p, scan channel p.
//   wave 4, q=lane: q<32 -> B/C col 512+q (conv -> LDS table); 32<=q<36 -> dt head q-32.
__global__ __launch_bounds__(320, 3) void k_fused(
    const float* __restrict__ x,        // [B,129,250]
    const float* __restrict__ w2t,      // [129,548]
    const float* __restrict__ bias2,    // [548]
    const float* __restrict__ conv_w,   // [288,4]
    const float* __restrict__ conv_b,   // [288]
    const float* __restrict__ dt_bias,  // [4]
    const float* __restrict__ A_log,    // [4]
    const float* __restrict__ Dv,       // [4]
    const float* __restrict__ norm_w,   // [256]
    const float* __restrict__ vv,       // [256]
    const float* __restrict__ head_b,   // [1]
    float* __restrict__ out)            // [B]
{
    __shared__ float sm_bc[TC][32];      // [tt][ 0..15 B | 16..31 C ]
    __shared__ float sm_dt[TC][NHEADS];
    __shared__ float sm_dA[TC][NHEADS];
    __shared__ float sm_part[TC][8];     // [tt][2w]=s1_w, [2w+1]=s2_w

    const int b    = blockIdx.x;
    const int tid  = threadIdx.x;
    const int lane = tid & 63;
    const int wv   = tid >> 6;           // 0..4
    const bool isMain = (wv < 4);
    const int p = tid;                   // main channel
    const int q = lane;                  // wave-4 role

    float bz = 0.f, bx = 0.f;
    float cw0 = 0.f, cw1 = 0.f, cw2 = 0.f, cw3 = 0.f, ccb = 0.f;
    float dtb = 0.f, Ah = 0.f, Dh = 0.f, nv = 0.f;
    int j1 = 0, j2 = 0;
    if (isMain) {
        j1 = p; j2 = DINNER + p;
        bz = bias2[j1]; bx = bias2[j2];
        cw0 = conv_w[p * 4 + 0]; cw1 = conv_w[p * 4 + 1];
        cw2 = conv_w[p * 4 + 2]; cw3 = conv_w[p * 4 + 3];
        ccb = conv_b[p];
        Dh = Dv[p >> 6];
        nv = norm_w[p] * vv[p];
    } else if (q < 36) {
        j2 = 2 * DINNER + q;
        bx = bias2[j2];
        if (q < 32) {
            int ch = DINNER + q;
            cw0 = conv_w[ch * 4 + 0]; cw1 = conv_w[ch * 4 + 1];
            cw2 = conv_w[ch * 4 + 2]; cw3 = conv_w[ch * 4 + 3];
            ccb = conv_b[ch];
        } else {
            int h = q - 32;
            dtb = dt_bias[h];
            Ah  = -expf(A_log[h]);
        }
    }

    float za[TC], xa[TC], hs[DSTATE];
    float h1 = 0.f, h2 = 0.f, h3 = 0.f, outacc = 0.f;
#pragma unroll
    for (int n = 0; n < DSTATE; ++n) hs[n] = 0.f;

    const float* xb = x + (size_t)b * NCH * NT;
    int t0 = 0;
    const int hh = p >> 6;   // head for main lanes (wave-uniform)

    auto body = [&](auto tclc) {
        constexpr int TCL = decltype(tclc)::value;
        // ---------------- GEMM: zx cols into registers ----------------
        if (isMain) {
#pragma unroll
            for (int tt = 0; tt < TCL; ++tt) { za[tt] = bz; xa[tt] = bx; }
            for (int c = 0; c < NCH; ++c) {
                const float* xr = xb + c * NT + t0;     // wave-uniform address
                float w1  = w2t[c * DPROJ + j1];
                float w2v = w2t[c * DPROJ + j2];
#pragma unroll
                for (int tt = 0; tt < TCL; ++tt) {
                    float xvv = xr[tt];
                    za[tt] = fmaf(w1,  xvv, za[tt]);
                    xa[tt] = fmaf(w2v, xvv, xa[tt]);
                }
            }
        } else if (q < 36) {
#pragma unroll
            for (int tt = 0; tt < TCL; ++tt) xa[tt] = bx;
            for (int c = 0; c < NCH; ++c) {
                const float* xr = xb + c * NT + t0;
                float w2v = w2t[c * DPROJ + j2];
#pragma unroll
                for (int tt = 0; tt < TCL; ++tt)
                    xa[tt] = fmaf(w2v, xr[tt], xa[tt]);
            }
        }
        // ---------------- conv + silu + gate + dt tables ----------------
        if (isMain) {
#pragma unroll
            for (int tt = 0; tt < TCL; ++tt) {
                float raw = xa[tt];
                float cv = fmaf(cw3, raw, fmaf(cw2, h1, fmaf(cw1, h2, fmaf(cw0, h3, ccb))));
                h3 = h2; h2 = h1; h1 = raw;
                xa[tt] = silu_f(cv);
                za[tt] = silu_f(za[tt]);
            }
        } else if (q < 32) {
#pragma unroll
            for (int tt = 0; tt < TCL; ++tt) {
                float raw = xa[tt];
                float cv = fmaf(cw3, raw, fmaf(cw2, h1, fmaf(cw1, h2, fmaf(cw0, h3, ccb))));
                h3 = h2; h2 = h1; h1 = raw;
                sm_bc[tt][q] = silu_f(cv);
            }
        } else if (q < 36) {
            int h = q - 32;
#pragma unroll
            for (int tt = 0; tt < TCL; ++tt) {
                float val = xa[tt] + dtb;
                float dt = (val > 20.f) ? val : log1pf(expf(val));
                sm_dt[tt][h] = dt;
                sm_dA[tt][h] = expf(dt * Ah);
            }
        }
        __syncthreads();
        // ---------------- scan + gated norm partials ----------------
        if (isMain) {
#pragma unroll
            for (int tt = 0; tt < TCL; ++tt) {
                float xv  = xa[tt];
                float g   = za[tt];
                float dtv = sm_dt[tt][hh];
                float dAv = sm_dA[tt][hh];
                float bcv = sm_bc[tt][lane & 31];   // 2-way broadcast, free
                float dx = dtv * xv;
                float y = 0.f;
#pragma unroll
                for (int n = 0; n < DSTATE; ++n) {
                    float Bn = rdlane(bcv, n);
                    float Cn = rdlane(bcv, DSTATE + n);
                    hs[n] = fmaf(hs[n], dAv, dx * Bn);
                    y = fmaf(hs[n], Cn, y);
                }
                float val = fmaf(Dh, xv, y) * g;
                float s1 = wave_sum63(val * val);
                float s2 = wave_sum63(val * nv);
                if (lane == 63) {
                    sm_part[tt][2 * wv]     = s1;
                    sm_part[tt][2 * wv + 1] = s2;
                }
            }
        }
        __syncthreads();
        // ---------------- fold per-tt totals (wave 4) ----------------
        if (!isMain && q < TCL) {
            float s1 = sm_part[q][0] + sm_part[q][2] + sm_part[q][4] + sm_part[q][6];
            float s2 = sm_part[q][1] + sm_part[q][3] + sm_part[q][5] + sm_part[q][7];
            outacc += s2 * rsqrtf(s1 * (1.f / DINNER) + 1e-5f);
        }
    };

    for (int ch = 0; ch < 7; ++ch) { body(IC<TC>{}); t0 += TC; }
    body(IC<26>{});

    if (!isMain) {
        float tot = wave_sum63(outacc);
        if (lane == 63) out[b] = head_b[0] + tot * (1.f / NT);
    }
}

extern "C" void kernel_launch(void* const* d_in, const int* in_sizes, int n_in,
                              void* d_out, int out_size, void* d_ws, size_t ws_size,
                              hipStream_t stream) {
    const float* x         = (const float*)d_in[0];
    const float* mixer_w   = (const float*)d_in[1];
    const float* mixer_b   = (const float*)d_in[2];
    const float* in_proj_w = (const float*)d_in[3];
    const float* conv_w    = (const float*)d_in[4];
    const float* conv_b    = (const float*)d_in[5];
    const float* dt_bias   = (const float*)d_in[6];
    const float* A_log     = (const float*)d_in[7];
    const float* Dp        = (const float*)d_in[8];
    const float* norm_w    = (const float*)d_in[9];
    const float* out_proj_w= (const float*)d_in[10];
    const float* head_w    = (const float*)d_in[11];
    const float* head_b    = (const float*)d_in[12];
    float* out = (float*)d_out;

    int B = in_sizes[0] / (NCH * NT);   // 512

    float* ws    = (float*)d_ws;
    float* w2t   = ws;                          // 129*548
    float* bias2 = w2t + (size_t)NCH * DPROJ;   // 548
    float* vvp   = bias2 + DPROJ;               // 256

    k_prep_w2<<<DPROJ, 256, 0, stream>>>(in_proj_w, mixer_w, mixer_b, w2t, bias2);
    k_prep_v<<<1, 256, 0, stream>>>(head_w, out_proj_w, vvp);
    k_fused<<<B, 320, 0, stream>>>(x, w2t, bias2, conv_w, conv_b, dt_bias,
                                   A_log, Dp, norm_w, vvp, head_b, out);
}

// Round 4
// 709.977 us; speedup vs baseline: 4.4796x; 2.4697x over previous
//
#include <hip/hip_runtime.h>
#include <math.h>

#define NCH     129
#define NT      250
#define DMODEL  128
#define DINNER  256
#define DSTATE  16
#define NHEADS  4
#define DPROJ   548   // z(256) + xh(256) + B(16) + C(16) + dt(4)
#define TC      16    // timestep chunk (250 = 15*16 + 10)

template<int N> struct IC { static constexpr int value = N; };

__device__ __forceinline__ float silu_f(float x) { return x / (1.f + __expf(-x)); }

// DPP butterfly: after 6 steps lane 63 holds the 64-lane sum (VALU pipe, no DS).
template<int CTRL>
__device__ __forceinline__ float dstep(float v) {
    int t = __builtin_amdgcn_update_dpp(0, __float_as_int(v), CTRL, 0xF, 0xF, true);
    return v + __int_as_float(t);
}
__device__ __forceinline__ float wave_sum63(float v) {
    v = dstep<0xB1>(v);   // quad_perm xor1
    v = dstep<0x4E>(v);   // quad_perm xor2
    v = dstep<0x141>(v);  // row_half_mirror
    v = dstep<0x140>(v);  // row_mirror
    v = dstep<0x142>(v);  // row_bcast15
    v = dstep<0x143>(v);  // row_bcast31 -> lane63 = total
    return v;
}
__device__ __forceinline__ float rdlane(float v, int l) {
    return __uint_as_float(__builtin_amdgcn_readlane(__float_as_uint(v), l));
}

// ---------- prep: W2t[c][j] = sum_d in_proj_w[j,d]*mixer_w[d,c]; bias2[j] ----------
__global__ __launch_bounds__(256) void k_prep_w2(const float* __restrict__ in_proj_w,
                                                 const float* __restrict__ mixer_w,
                                                 const float* __restrict__ mixer_b,
                                                 float* __restrict__ w2t,
                                                 float* __restrict__ bias2) {
    int j = blockIdx.x;
    int c = threadIdx.x;
    if (c < NCH) {
        float acc = 0.f;
        for (int d = 0; d < DMODEL; ++d)
            acc += in_proj_w[j * DMODEL + d] * mixer_w[d * NCH + c];
        w2t[(size_t)c * DPROJ + j] = acc;
    } else if (c == NCH) {
        float acc = 0.f;
        for (int d = 0; d < DMODEL; ++d)
            acc += in_proj_w[j * DMODEL + d] * mixer_b[d];
        bias2[j] = acc;
    }
}

// ---------- prep: v[i] = sum_d head_w[0,d]*out_proj_w[d,i] ----------
__global__ __launch_bounds__(256) void k_prep_v(const float* __restrict__ head_w,
                                                const float* __restrict__ out_proj_w,
                                                float* __restrict__ v) {
    int i = threadIdx.x;
    float acc = 0.f;
    for (int d = 0; d < DMODEL; ++d)
        acc += head_w[d] * out_proj_w[(size_t)d * DINNER + i];
    v[i] = acc;
}

// ---------- fully fused pipeline, one block per batch element, 320 thr = 5 waves ----------
__global__ __launch_bounds__(320, 2) void k_fused(
    const float* __restrict__ x,        // [B,129,250]
    const float* __restrict__ w2t,      // [129,548]
    const float* __restrict__ bias2,    // [548]
    const float* __restrict__ conv_w,   // [288,4]
    const float* __restrict__ conv_b,   // [288]
    const float* __restrict__ dt_bias,  // [4]
    const float* __restrict__ A_log,    // [4]
    const float* __restrict__ Dv,       // [4]
    const float* __restrict__ norm_w,   // [256]
    const float* __restrict__ vv,       // [256]
    const float* __restrict__ head_b,   // [1]
    float* __restrict__ out)            // [B]
{
    __shared__ float sm_bc[TC][32];      // [tt][ 0..15 B | 16..31 C ]
    __shared__ float sm_dt[TC][NHEADS];
    __shared__ float sm_dA[TC][NHEADS];
    __shared__ float sm_part[TC][8];

    const int b    = blockIdx.x;
    const int tid  = threadIdx.x;
    const int lane = tid & 63;
    const int wv   = tid >> 6;
    const bool isMain = (wv < 4);
    const int p = tid;
    const int q = lane;

    float bz = 0.f, bx = 0.f;
    float cw0 = 0.f, cw1 = 0.f, cw2 = 0.f, cw3 = 0.f, ccb = 0.f;
    float dtb = 0.f, Ah = 0.f, Dh = 0.f, nv = 0.f;
    int j1 = 0, j2 = 0;
    if (isMain) {
        j1 = p; j2 = DINNER + p;
        bz = bias2[j1]; bx = bias2[j2];
        cw0 = conv_w[p * 4 + 0]; cw1 = conv_w[p * 4 + 1];
        cw2 = conv_w[p * 4 + 2]; cw3 = conv_w[p * 4 + 3];
        ccb = conv_b[p];
        Dh = Dv[p >> 6];
        nv = norm_w[p] * vv[p];
    } else if (q < 36) {
        j2 = 2 * DINNER + q;
        bx = bias2[j2];
        if (q < 32) {
            int ch = DINNER + q;
            cw0 = conv_w[ch * 4 + 0]; cw1 = conv_w[ch * 4 + 1];
            cw2 = conv_w[ch * 4 + 2]; cw3 = conv_w[ch * 4 + 3];
            ccb = conv_b[ch];
        } else {
            int h = q - 32;
            dtb = dt_bias[h];
            Ah  = -expf(A_log[h]);
        }
    }

    float za[TC], xa[TC], hs[DSTATE];
    float h1 = 0.f, h2 = 0.f, h3 = 0.f, outacc = 0.f;
#pragma unroll
    for (int n = 0; n < DSTATE; ++n) hs[n] = 0.f;

    const float* xb = x + (size_t)b * NCH * NT;
    int t0 = 0;
    const int hh = p >> 6;

    auto body = [&](auto tclc) {
        constexpr int TCL = decltype(tclc)::value;
        // ---------------- GEMM chunk into registers ----------------
        if (isMain) {
#pragma unroll
            for (int tt = 0; tt < TCL; ++tt) { za[tt] = bz; xa[tt] = bx; }
            for (int c = 0; c < NCH; ++c) {
                const float* xr = xb + c * NT + t0;     // wave-uniform
                float w1  = w2t[c * DPROJ + j1];
                float w2v = w2t[c * DPROJ + j2];
#pragma unroll
                for (int tt = 0; tt < TCL; ++tt) {
                    float xvv = xr[tt];
                    za[tt] = fmaf(w1,  xvv, za[tt]);
                    xa[tt] = fmaf(w2v, xvv, xa[tt]);
                }
            }
        } else if (q < 36) {
#pragma unroll
            for (int tt = 0; tt < TCL; ++tt) xa[tt] = bx;
            for (int c = 0; c < NCH; ++c) {
                const float* xr = xb + c * NT + t0;
                float w2v = w2t[c * DPROJ + j2];
#pragma unroll
                for (int tt = 0; tt < TCL; ++tt)
                    xa[tt] = fmaf(w2v, xr[tt], xa[tt]);
            }
        }
        // ---------------- conv + silu + dt tables ----------------
        if (isMain) {
#pragma unroll
            for (int tt = 0; tt < TCL; ++tt) {
                float raw = xa[tt];
                float cv = fmaf(cw3, raw, fmaf(cw2, h1, fmaf(cw1, h2, fmaf(cw0, h3, ccb))));
                h3 = h2; h2 = h1; h1 = raw;
                xa[tt] = silu_f(cv);
                za[tt] = silu_f(za[tt]);
            }
        } else if (q < 32) {
#pragma unroll
            for (int tt = 0; tt < TCL; ++tt) {
                float raw = xa[tt];
                float cv = fmaf(cw3, raw, fmaf(cw2, h1, fmaf(cw1, h2, fmaf(cw0, h3, ccb))));
                h3 = h2; h2 = h1; h1 = raw;
                sm_bc[tt][q] = silu_f(cv);
            }
        } else if (q < 36) {
            int h = q - 32;
#pragma unroll
            for (int tt = 0; tt < TCL; ++tt) {
                float val = xa[tt] + dtb;
                float dt = (val > 20.f) ? val : log1pf(expf(val));
                sm_dt[tt][h] = dt;
                sm_dA[tt][h] = __expf(dt * Ah);
            }
        }
        __syncthreads();
        // ---------------- scan + gated-norm partials ----------------
        if (isMain) {
#pragma unroll
            for (int tt = 0; tt < TCL; ++tt) {
                float xv  = xa[tt];
                float g   = za[tt];
                float dtv = sm_dt[tt][hh];
                float dAv = sm_dA[tt][hh];
                float bcv = sm_bc[tt][lane & 31];   // 2-way broadcast, free
                float dx = dtv * xv;
                float y = 0.f;
#pragma unroll
                for (int n = 0; n < DSTATE; ++n) {
                    float Bn = rdlane(bcv, n);
                    float Cn = rdlane(bcv, DSTATE + n);
                    hs[n] = fmaf(hs[n], dAv, dx * Bn);
                    y = fmaf(hs[n], Cn, y);
                }
                float val = fmaf(Dh, xv, y) * g;
                float s1 = wave_sum63(val * val);
                float s2 = wave_sum63(val * nv);
                if (lane == 63) {
                    sm_part[tt][2 * wv]     = s1;
                    sm_part[tt][2 * wv + 1] = s2;
                }
            }
        }
        __syncthreads();
        // ---------------- fold per-tt totals (wave 4) ----------------
        if (!isMain && q < TCL) {
            float s1 = sm_part[q][0] + sm_part[q][2] + sm_part[q][4] + sm_part[q][6];
            float s2 = sm_part[q][1] + sm_part[q][3] + sm_part[q][5] + sm_part[q][7];
            outacc += s2 * rsqrtf(s1 * (1.f / DINNER) + 1e-5f);
        }
    };

    for (int ch = 0; ch < 15; ++ch) { body(IC<TC>{}); t0 += TC; }
    body(IC<10>{});

    if (!isMain) {
        float tot = wave_sum63(outacc);
        if (lane == 63) out[b] = head_b[0] + tot * (1.f / NT);
    }
}

extern "C" void kernel_launch(void* const* d_in, const int* in_sizes, int n_in,
                              void* d_out, int out_size, void* d_ws, size_t ws_size,
                              hipStream_t stream) {
    const float* x         = (const float*)d_in[0];
    const float* mixer_w   = (const float*)d_in[1];
    const float* mixer_b   = (const float*)d_in[2];
    const float* in_proj_w = (const float*)d_in[3];
    const float* conv_w    = (const float*)d_in[4];
    const float* conv_b    = (const float*)d_in[5];
    const float* dt_bias   = (const float*)d_in[6];
    const float* A_log     = (const float*)d_in[7];
    const float* Dp        = (const float*)d_in[8];
    const float* norm_w    = (const float*)d_in[9];
    const float* out_proj_w= (const float*)d_in[10];
    const float* head_w    = (const float*)d_in[11];
    const float* head_b    = (const float*)d_in[12];
    float* out = (float*)d_out;

    int B = in_sizes[0] / (NCH * NT);   // 512

    float* ws    = (float*)d_ws;
    float* w2t   = ws;                          // 129*548
    float* bias2 = w2t + (size_t)NCH * DPROJ;   // 548
    float* vvp   = bias2 + DPROJ;               // 256

    k_prep_w2<<<DPROJ, 256, 0, stream>>>(in_proj_w, mixer_w, mixer_b, w2t, bias2);
    k_prep_v<<<1, 256, 0, stream>>>(head_w, out_proj_w, vvp);
    k_fused<<<B, 320, 0, stream>>>(x, w2t, bias2, conv_w, conv_b, dt_bias,
                                   A_log, Dp, norm_w, vvp, head_b, out);
}